// Round 15
// baseline (44.532 us; speedup 1.0000x reference)
//
#include <hip/hip_runtime.h>
#include <stdint.h>

#define B_N 16
#define C_N 64
#define O_N 64
#define H_N 128
#define W_N 128

typedef short bf16x8 __attribute__((ext_vector_type(8)));
typedef float f32x4 __attribute__((ext_vector_type(4)));
typedef unsigned short u16;
typedef u16 u16x4 __attribute__((ext_vector_type(4)));
typedef u16 u16x8 __attribute__((ext_vector_type(8)));

__device__ __forceinline__ u16 f2bf(float f) {
    uint32_t u = __float_as_uint(f);
    u += 0x7FFFu + ((u >> 16) & 1u);
    return (u16)(u >> 16);
}

// Period-8 swizzle: conflict-free b128 reads on every 8-w window (incl. the
// jsh=+-1 shifted windows). RULE (R8): XOR the COMPLETE in-row offset.
__device__ __forceinline__ int swz(int w) { return (w & 7) << 4; }

// Main kernel v14: FAT-WAVE variant of the v12 champion.
// KEY INSIGHT (R13 post-mortem): a 512-thread block physically requires
// 2 waves/SIMD -> hard 256-reg/wave cap (this, not the allocator, caused
// every spill failure R2/R7/R8/R13). A 256-thread block (4 waves = 1/SIMD)
// may hold ~512 regs/wave -> wreg[9][2][4] = 288 regs is feasible.
// Each wave now owns the FULL o=64 range: every A-fragment feeds 4 MFMAs
// (was 2) -> A-side ds_read_b128 per CU-row HALVES (288 -> 144), attacking
// the busiest shared pipe (LDS ~17us of 32.5). Per (ij,cs) step: 2 reads +
// 8 MFMAs -> ample ILP for compiler lgkmcnt pipelining at 1 wave/SIMD.
// Chassis unchanged from v12: grid 256 (8-row strips), 6 LDS row-slots
// (96 KB), conflict-free fused ingest, restage s=r+4 at ij0 / load s=r+5
// at ij3, barrier every 2 rows.
// Register ledger: 288 wreg + 32 acc + <=96 staging holds + ~40 addr ~ 424
// peak < 450 (m08 no-spill bound). Tripwire: WRITE_SIZE > 70 MB = spilled.
__global__ __launch_bounds__(256, 1) void conv_main(const float* __restrict__ x,
                                                    const float* __restrict__ wt,
                                                    const float* __restrict__ bias,
                                                    float* __restrict__ y) {
    __shared__ u16 xl[6 * 128 * 64];   // 6 slots x [w][c] bf16 = 96 KB, swz

    // XCD-bijective swizzle: 256 wgs, 8 XCDs, chunk 32 -> XCD j owns 2 full b's.
    const int lid = (blockIdx.x & 7) * 32 + (blockIdx.x >> 3);
    const int b   = lid >> 4;
    const int h0  = (lid & 15) * 8;
    const int tid = threadIdx.x;
    const int wid = tid >> 6;
    const int l   = tid & 63;
    const int m0  = wid * 32;                 // wave owns 32 px x ALL 64 o
    const int lr  = l & 15;
    const int lg  = l >> 4;

    // staging task: 32 w-quads x 8 cq2 (2 c-quads each) = 256 threads/row
    const int w4  = tid & 31;
    const int cq2 = tid >> 5;                 // 0..7
    const float* xb  = x  + (size_t)b * (64 * 128 * 128);
    const float* wtb = wt + (size_t)b * (576 * 64);

    auto ldrow = [&](int s, f32x4* d) {
        int hr = (h0 + s + 127) & 127;        // input row h0 + s - 1 (wrap)
#pragma unroll
        for (int half = 0; half < 2; ++half) {
            const float* src = xb + ((size_t)(cq2 * 2 + half) * 4 * 128 + hr) * 128 + w4 * 4;
            d[half * 4 + 0] = *reinterpret_cast<const f32x4*>(src);
            d[half * 4 + 1] = *reinterpret_cast<const f32x4*>(src + 16384);
            d[half * 4 + 2] = *reinterpret_cast<const f32x4*>(src + 32768);
            d[half * 4 + 3] = *reinterpret_cast<const f32x4*>(src + 49152);
        }
    };
    auto wrrow = [&](int slot, const f32x4* d) {   // slot = staged-row % 6
#pragma unroll
        for (int half = 0; half < 2; ++half) {
            const int cq = cq2 * 2 + half;
#pragma unroll
            for (int j = 0; j < 4; ++j) {
                int w = w4 * 4 + j;
                u16x4 pk;
                pk.x = f2bf(d[half * 4 + 0][j]); pk.y = f2bf(d[half * 4 + 1][j]);
                pk.z = f2bf(d[half * 4 + 2][j]); pk.w = f2bf(d[half * 4 + 3][j]);
                int byte = slot * 16384 + w * 128 + ((cq * 8) ^ swz(w));
                *reinterpret_cast<u16x4*>(reinterpret_cast<char*>(xl) + byte) = pk;
            }
        }
    };

    // ---- x rows 0..1 issued FIRST: HBM latency hides under the ingest ----
    f32x4 sA[8], sB[8], st[8];
    ldrow(0, sA); ldrow(1, sB);

    // ---- Fused weight ingest, prep-orientation (R12-verified, conflict-free):
    //      strided dword reads + ONE linear ds_write_b128 per thread ----
    u16* wl = xl;                             // 36864 u16 = 72 KB scratch
#pragma unroll
    for (int it = 0; it < 18; ++it) {
        int task = it * 256 + tid;            // < 4608 = 9ij * 2cs * 4of * 64l
        int tl = task & 63;
        int of = (task >> 6) & 3;
        int cs = (task >> 8) & 1;
        int ij = task >> 9;                   // 0..8
        const int o = of * 16 + (tl & 15);
        const int cbase = cs * 32 + (tl >> 4) * 8;
        u16x8 pk;
#pragma unroll
        for (int j8 = 0; j8 < 8; ++j8) {
            float v = wtb[(size_t)(cbase + j8) * 9 * 64 + (size_t)ij * 64 + o];
            pk[j8] = f2bf(v);
        }
        *reinterpret_cast<u16x8*>(wl + (size_t)task * 8) = pk;
    }
    __syncthreads();                          // wl fully written

    bf16x8 wreg[9][2][4];                     // [ij][cs][nf] = 288 regs
#pragma unroll
    for (int ij = 0; ij < 9; ++ij)
#pragma unroll
        for (int cs = 0; cs < 2; ++cs)
#pragma unroll
            for (int nf = 0; nf < 4; ++nf)
                wreg[ij][cs][nf] = *reinterpret_cast<const bf16x8*>(
                    wl + (size_t)(((ij * 2 + cs) * 4 + nf) * 64 + l) * 8);

    float bv[4];
#pragma unroll
    for (int nf = 0; nf < 4; ++nf) bv[nf] = bias[b * 64 + nf * 16 + lr];
    __syncthreads();                          // wreg reads done; recycle LDS

    // ---- Prologue staging: slots 0..4, staged 4 held in regs for row 0 ----
    wrrow(0, sA); wrrow(1, sB);
    ldrow(2, sA); ldrow(3, sB); ldrow(4, st);
    wrrow(2, sA); wrrow(3, sB);
    __syncthreads();

    // ---- 8 output rows; row r reads slots (r..r+2)%6 ----
    int slA = 0;                              // r % 6, tracked incrementally
#pragma unroll 1
    for (int r = 0; r < 8; ++r) {
        const int slB = (slA + 1 == 6) ? 0 : slA + 1;
        const int slC = (slB + 1 == 6) ? 0 : slB + 1;
        const int slW = (slC + 2 >= 6) ? slC + 2 - 6 : slC + 2;   // (r+4)%6
        const int base0 = slA * 16384, base1 = slB * 16384, base2 = slC * 16384;

        f32x4 acc[2][4];
#pragma unroll
        for (int mf = 0; mf < 2; ++mf)
#pragma unroll
            for (int nf = 0; nf < 4; ++nf)
                acc[mf][nf] = (f32x4){0.f, 0.f, 0.f, 0.f};

#pragma unroll
        for (int ij = 0; ij < 9; ++ij) {
            if (ij == 0 && r < 6) wrrow(slW, st);     // data loaded last row
            if (ij == 3 && r < 5) ldrow(r + 5, st);   // consumed next row

            const int i = ij / 3;
            const int jsh = ij % 3 - 1;
            const int rbase = (i == 0) ? base0 : (i == 1) ? base1 : base2;
#pragma unroll
            for (int cs = 0; cs < 2; ++cs) {
                const int cb = cs * 64 + lg * 16;
                bf16x8 afr[2];
#pragma unroll
                for (int mf = 0; mf < 2; ++mf) {
                    int w = (m0 + mf * 16 + lr + jsh + 128) & 127;
                    int byte = rbase + w * 128 + (cb ^ swz(w));
                    afr[mf] = *reinterpret_cast<const bf16x8*>(
                        reinterpret_cast<const char*>(xl) + byte);
                }
#pragma unroll
                for (int mf = 0; mf < 2; ++mf)
#pragma unroll
                    for (int nf = 0; nf < 4; ++nf)
                        acc[mf][nf] = __builtin_amdgcn_mfma_f32_16x16x32_bf16(
                            afr[mf], wreg[ij][cs][nf], acc[mf][nf], 0, 0, 0);
            }
        }

        // ---- Epilogue: D layout col=lane&15 (o), row=(lane>>4)*4+reg (w) ----
        const int h = h0 + r;
#pragma unroll
        for (int nf = 0; nf < 4; ++nf) {
            int o = nf * 16 + lr;
#pragma unroll
            for (int mf = 0; mf < 2; ++mf) {
                int w0 = m0 + mf * 16 + lg * 4;
                float* dst = y + (((size_t)b * 64 + o) * 128 + h) * 128 + w0;
                f32x4 out;
                out[0] = acc[mf][nf][0] + bv[nf];
                out[1] = acc[mf][nf][1] + bv[nf];
                out[2] = acc[mf][nf][2] + bv[nf];
                out[3] = acc[mf][nf][3] + bv[nf];
                *reinterpret_cast<f32x4*>(dst) = out;
            }
        }

        // Barrier every 2 rows (after rows 1,3,5). Hazard ledger: a slot
        // written at row r is first read at row r+2 and last-read-before-
        // overwrite at row r-2 -> one barrier inside each 2-row window in
        // both directions suffices (checked per slot for r=0..7).
        if ((r & 1) && r < 7) __syncthreads();
        slA = slB;
    }
}

extern "C" void kernel_launch(void* const* d_in, const int* in_sizes, int n_in,
                              void* d_out, int out_size, void* d_ws, size_t ws_size,
                              hipStream_t stream) {
    const float* x    = (const float*)d_in[0];
    const float* wt   = (const float*)d_in[1];
    const float* bias = (const float*)d_in[2];
    float* y = (float*)d_out;
    (void)d_ws; (void)ws_size;                // fused kernel needs no workspace

    hipLaunchKernelGGL(conv_main, dim3(B_N * H_N / 8), dim3(256), 0, stream,
                       x, wt, bias, y);
}

// Round 16
// 33.123 us; speedup vs baseline: 1.3445x; 1.3445x over previous
//
#include <hip/hip_runtime.h>
#include <stdint.h>

#define B_N 16
#define C_N 64
#define O_N 64
#define H_N 128
#define W_N 128

typedef short bf16x8 __attribute__((ext_vector_type(8)));
typedef float f32x4 __attribute__((ext_vector_type(4)));
typedef unsigned short u16;
typedef u16 u16x4 __attribute__((ext_vector_type(4)));
typedef u16 u16x8 __attribute__((ext_vector_type(8)));

__device__ __forceinline__ u16 f2bf(float f) {
    uint32_t u = __float_as_uint(f);
    u += 0x7FFFu + ((u >> 16) & 1u);
    return (u16)(u >> 16);
}

// Period-8 swizzle: conflict-free b128 reads on every 8-w window (incl. the
// jsh=+-1 shifted windows). Staging writes pay ~28 cyc/store (R0/R1 ledger)
// — accepted (LDS pipe not the bottleneck; R4->R5 flatness proved it).
// RULE (R8): XOR the COMPLETE in-row offset — adds after the XOR can carry
// into the w-row bit.
__device__ __forceinline__ int swz(int w) { return (w & 7) << 4; }

// Main kernel v12 (SESSION FINAL — benched 32.58us R12, 32.51us R14).
// v7 champion chassis + fused weight transform with conflict-free ingest
// orientation (strided dword reads + ONE linear ds_write_b128 per thread).
// Chassis: 8-row strips, grid 256, 512 thr (8 waves x 32px x 32o), wreg
// B-frags in registers (144), 6 LDS row-slots (96 KB; 1 block/CU, 2
// waves/SIMD), restage s=r+4 write at ij0 / s=r+5 load at ij3, barrier
// every 2 rows.
// Why this is the plateau (all measured): waves/SIMD up (R3 -72%), down
// (R15 fat-wave -57%: 1 wave/SIMD exposes all latency), independent-block
// stagger (R9 -17%), deeper pipeline / fewer barriers (R6 ~0), LDS B-traffic
// -50% (R5 ~0), LDS A-traffic -67% (R13 spill: 512-thr blocks cap 256
// regs/wave), ingest orientation flip (R11 -14% via 4.4M bank conflicts).
// The 2-waves/SIMD requirement (for latency self-cover) caps registers,
// which caps fragment residency — the remaining ~15us over the ~17us
// traffic floor is the staging->barrier->compute cadence itself.
__global__ __launch_bounds__(512, 2) void conv_main(const float* __restrict__ x,
                                                    const float* __restrict__ wt,
                                                    const float* __restrict__ bias,
                                                    float* __restrict__ y) {
    __shared__ u16 xl[6 * 128 * 64];   // 6 slots x [w][c] bf16 = 96 KB, swz

    // XCD-bijective swizzle: 256 wgs, 8 XCDs, chunk 32 -> XCD j owns 2 full b's.
    const int lid = (blockIdx.x & 7) * 32 + (blockIdx.x >> 3);
    const int b   = lid >> 4;
    const int h0  = (lid & 15) * 8;
    const int tid = threadIdx.x;
    const int wid = tid >> 6;
    const int l   = tid & 63;
    const int wave_m = wid >> 1;              // 0..3 -> 32-px band
    const int wave_n = wid & 1;               // 0..1 -> 32-o band
    const int m0 = wave_m * 32;
    const int o0 = wave_n * 32;
    const int lr = l & 15;
    const int lg = l >> 4;

    // staging task: 32 w-quads x 16 c-quads = 512 threads, full row per pass
    const int w4 = tid & 31;
    const int cq = tid >> 5;                  // 0..15
    const float* xb  = x  + (size_t)b * (64 * 128 * 128);
    const float* wtb = wt + (size_t)b * (576 * 64);

    auto ldrow = [&](int s, f32x4* d) {
        int hr = (h0 + s + 127) & 127;        // input row h0 + s - 1 (wrap)
        const float* src = xb + ((size_t)cq * 4 * 128 + hr) * 128 + w4 * 4;
        d[0] = *reinterpret_cast<const f32x4*>(src);
        d[1] = *reinterpret_cast<const f32x4*>(src + 16384);
        d[2] = *reinterpret_cast<const f32x4*>(src + 32768);
        d[3] = *reinterpret_cast<const f32x4*>(src + 49152);
    };
    auto wrrow = [&](int slot, const f32x4* d) {   // slot = staged-row % 6
#pragma unroll
        for (int j = 0; j < 4; ++j) {
            int w = w4 * 4 + j;
            u16x4 pk;
            pk.x = f2bf(d[0][j]); pk.y = f2bf(d[1][j]);
            pk.z = f2bf(d[2][j]); pk.w = f2bf(d[3][j]);
            int byte = slot * 16384 + w * 128 + ((cq * 8) ^ swz(w));
            *reinterpret_cast<u16x4*>(reinterpret_cast<char*>(xl) + byte) = pk;
        }
    };

    // ---- x rows 0..2 issued FIRST: HBM latency hides under the ingest ----
    f32x4 s0[4], s1[4], s2[4], st[4];
    ldrow(0, s0); ldrow(1, s1); ldrow(2, s2);

    // ---- Fused weight ingest, prep-orientation (R12-verified mapping):
    //      thread owns fragment-slot idx = ((ij*2+cs)*4+of)*64 + l per iter;
    //      8 strided dword reads (c = cs*32 + (l>>4)*8 + j8, o = of*16+(l&15)),
    //      pack u16x8, ONE linear ds_write_b128 at idx*16 (conflict-free).
    u16* wl = xl;                             // 36864 u16 = 72 KB scratch
#pragma unroll
    for (int it = 0; it < 9; ++it) {
        int task = it * 512 + tid;            // < 4608 = 9ij * 2cs * 4of * 64l
        int tl = task & 63;
        int of = (task >> 6) & 3;
        int cs = (task >> 8) & 1;
        int ij = task >> 9;                   // 0..8
        const int o = of * 16 + (tl & 15);
        const int cbase = cs * 32 + (tl >> 4) * 8;
        u16x8 pk;
#pragma unroll
        for (int j8 = 0; j8 < 8; ++j8) {
            float v = wtb[(size_t)(cbase + j8) * 9 * 64 + (size_t)ij * 64 + o];
            pk[j8] = f2bf(v);
        }
        *reinterpret_cast<u16x8*>(wl + (size_t)task * 8) = pk;
    }
    __syncthreads();                          // wl fully written

    bf16x8 wreg[9][2][2];                     // [ij][cs][nf] = 144 regs
#pragma unroll
    for (int ij = 0; ij < 9; ++ij)
#pragma unroll
        for (int cs = 0; cs < 2; ++cs)
#pragma unroll
            for (int nf = 0; nf < 2; ++nf)
                wreg[ij][cs][nf] = *reinterpret_cast<const bf16x8*>(
                    wl + (size_t)(((ij * 2 + cs) * 4 + wave_n * 2 + nf) * 64 + l) * 8);

    const float bv0 = bias[b * 64 + o0 + lr];
    const float bv1 = bias[b * 64 + o0 + 16 + lr];
    __syncthreads();                          // wreg reads done; recycle LDS

    // ---- Prologue staging: slots 0..3, s=4 held in regs for row 0 ----
    wrrow(0, s0); wrrow(1, s1); wrrow(2, s2);
    ldrow(3, s0); ldrow(4, st);
    wrrow(3, s0);
    __syncthreads();

    // ---- 8 output rows; row r reads slots (r..r+2)%6 ----
    int slA = 0;                              // r % 6, tracked incrementally
#pragma unroll 1
    for (int r = 0; r < 8; ++r) {
        const int slB = (slA + 1 == 6) ? 0 : slA + 1;
        const int slC = (slB + 1 == 6) ? 0 : slB + 1;
        const int slW = (slC + 2 >= 6) ? slC + 2 - 6 : slC + 2;   // (r+4)%6
        const int base0 = slA * 16384, base1 = slB * 16384, base2 = slC * 16384;

        f32x4 acc[2][2];
#pragma unroll
        for (int mf = 0; mf < 2; ++mf)
#pragma unroll
            for (int nf = 0; nf < 2; ++nf)
                acc[mf][nf] = (f32x4){0.f, 0.f, 0.f, 0.f};

#pragma unroll
        for (int ij = 0; ij < 9; ++ij) {
            if (ij == 0 && r < 6) wrrow(slW, st);     // data loaded last row
            if (ij == 3 && r < 5) ldrow(r + 5, st);   // consumed next row

            const int i = ij / 3;
            const int jsh = ij % 3 - 1;
            const int rbase = (i == 0) ? base0 : (i == 1) ? base1 : base2;
#pragma unroll
            for (int cs = 0; cs < 2; ++cs) {
                const int cb = cs * 64 + lg * 16;
                bf16x8 afr[2];
#pragma unroll
                for (int mf = 0; mf < 2; ++mf) {
                    int w = (m0 + mf * 16 + lr + jsh + 128) & 127;
                    int byte = rbase + w * 128 + (cb ^ swz(w));
                    afr[mf] = *reinterpret_cast<const bf16x8*>(
                        reinterpret_cast<const char*>(xl) + byte);
                }
#pragma unroll
                for (int mf = 0; mf < 2; ++mf) {
                    acc[mf][0] = __builtin_amdgcn_mfma_f32_16x16x32_bf16(afr[mf], wreg[ij][cs][0], acc[mf][0], 0, 0, 0);
                    acc[mf][1] = __builtin_amdgcn_mfma_f32_16x16x32_bf16(afr[mf], wreg[ij][cs][1], acc[mf][1], 0, 0, 0);
                }
            }
        }

        // ---- Epilogue: D layout col=lane&15 (o), row=(lane>>4)*4+reg (w) ----
        const int h = h0 + r;
#pragma unroll
        for (int nf = 0; nf < 2; ++nf) {
            int o = o0 + nf * 16 + lr;
            float bv = nf ? bv1 : bv0;
#pragma unroll
            for (int mf = 0; mf < 2; ++mf) {
                int w0 = m0 + mf * 16 + lg * 4;
                float* dst = y + (((size_t)b * 64 + o) * 128 + h) * 128 + w0;
                f32x4 out;
                out[0] = acc[mf][nf][0] + bv;
                out[1] = acc[mf][nf][1] + bv;
                out[2] = acc[mf][nf][2] + bv;
                out[3] = acc[mf][nf][3] + bv;
                *reinterpret_cast<f32x4*>(dst) = out;
            }
        }

        // Barrier every 2 rows (after rows 1,3,5). Hazard ledger: a slot
        // written at row r is first read at row r+2 and last-read-before-
        // overwrite at row r-2 -> one barrier inside each 2-row window in
        // both directions suffices (checked per slot for r=0..7).
        if ((r & 1) && r < 7) __syncthreads();
        slA = slB;
    }
}

extern "C" void kernel_launch(void* const* d_in, const int* in_sizes, int n_in,
                              void* d_out, int out_size, void* d_ws, size_t ws_size,
                              hipStream_t stream) {
    const float* x    = (const float*)d_in[0];
    const float* wt   = (const float*)d_in[1];
    const float* bias = (const float*)d_in[2];
    float* y = (float*)d_out;
    (void)d_ws; (void)ws_size;                // fused kernel needs no workspace

    hipLaunchKernelGGL(conv_main, dim3(B_N * H_N / 8), dim3(512), 0, stream,
                       x, wt, bias, y);
}

// Round 17
// 32.125 us; speedup vs baseline: 1.3862x; 1.0311x over previous
//
#include <hip/hip_runtime.h>
#include <stdint.h>

#define B_N 16
#define C_N 64
#define O_N 64
#define H_N 128
#define W_N 128

typedef short bf16x8 __attribute__((ext_vector_type(8)));
typedef float f32x4 __attribute__((ext_vector_type(4)));
typedef unsigned short u16;
typedef u16 u16x4 __attribute__((ext_vector_type(4)));
typedef u16 u16x8 __attribute__((ext_vector_type(8)));

__device__ __forceinline__ u16 f2bf(float f) {
    uint32_t u = __float_as_uint(f);
    u += 0x7FFFu + ((u >> 16) & 1u);
    return (u16)(u >> 16);
}

// Period-8 swizzle: conflict-free b128 reads on every 8-w window (incl. the
// jsh=+-1 shifted windows). RULE (R8): XOR the COMPLETE in-row offset — adds
// after the XOR can carry into the w-row bit.
__device__ __forceinline__ int swz(int w) { return (w & 7) << 4; }

// Main kernel v12p (v12 + staging LANE PERMUTATION, final).
// v12 chassis, benched 32.58/32.51/33.12us: 8-row strips, grid 256, 512 thr
// (8 waves x 32px x 32o), wreg B-frags in registers (144), 6 LDS row-slots
// (96 KB; 1 block/CU, 2 waves/SIMD), fused conflict-free weight ingest,
// restage s=r+4 write at ij0 / s=r+5 load at ij3, barrier every 2 rows.
// v12p change: staging task assignment w4=(tid>>7)<<3|(tid&7), cq=(tid>>3)&15
// -> a wave spans 8 cq values instead of 2, spreading wrrow's b64 writes
// over 16 bank-slots (4-way, the b64 floor) instead of 4 (16-way). Pure
// bijective lane permutation: write byte-set identical, global-read
// coalescing identical (8 x 128B line-segments per ldrow instr either way).
// Session ledger (all measured, flat-to-negative): waves/SIMD up (R3),
// down/fat-wave (R15), block-stagger (R9), deeper pipeline + fewer barriers
// (R6), LDS B-traffic -50% (R5), LDS A-traffic -67% (R13 spill), ingest
// orientation (R11/R12). Remaining ~15us over the traffic floor is the
// staging->barrier->compute cadence at the forced 2-waves/SIMD point.
__global__ __launch_bounds__(512, 2) void conv_main(const float* __restrict__ x,
                                                    const float* __restrict__ wt,
                                                    const float* __restrict__ bias,
                                                    float* __restrict__ y) {
    __shared__ u16 xl[6 * 128 * 64];   // 6 slots x [w][c] bf16 = 96 KB, swz

    // XCD-bijective swizzle: 256 wgs, 8 XCDs, chunk 32 -> XCD j owns 2 full b's.
    const int lid = (blockIdx.x & 7) * 32 + (blockIdx.x >> 3);
    const int b   = lid >> 4;
    const int h0  = (lid & 15) * 8;
    const int tid = threadIdx.x;
    const int wid = tid >> 6;
    const int l   = tid & 63;
    const int wave_m = wid >> 1;              // 0..3 -> 32-px band
    const int wave_n = wid & 1;               // 0..1 -> 32-o band
    const int m0 = wave_m * 32;
    const int o0 = wave_n * 32;
    const int lr = l & 15;
    const int lg = l >> 4;

    // staging task (v12p permutation): wave spans w4lo 0..7 x cq 0..7 ->
    // wrrow 4-way banked (was 16-way); ldrow still 8x128B segments/instr.
    const int w4 = ((tid >> 7) << 3) | (tid & 7);
    const int cq = (tid >> 3) & 15;
    const float* xb  = x  + (size_t)b * (64 * 128 * 128);
    const float* wtb = wt + (size_t)b * (576 * 64);

    auto ldrow = [&](int s, f32x4* d) {
        int hr = (h0 + s + 127) & 127;        // input row h0 + s - 1 (wrap)
        const float* src = xb + ((size_t)cq * 4 * 128 + hr) * 128 + w4 * 4;
        d[0] = *reinterpret_cast<const f32x4*>(src);
        d[1] = *reinterpret_cast<const f32x4*>(src + 16384);
        d[2] = *reinterpret_cast<const f32x4*>(src + 32768);
        d[3] = *reinterpret_cast<const f32x4*>(src + 49152);
    };
    auto wrrow = [&](int slot, const f32x4* d) {   // slot = staged-row % 6
#pragma unroll
        for (int j = 0; j < 4; ++j) {
            int w = w4 * 4 + j;
            u16x4 pk;
            pk.x = f2bf(d[0][j]); pk.y = f2bf(d[1][j]);
            pk.z = f2bf(d[2][j]); pk.w = f2bf(d[3][j]);
            int byte = slot * 16384 + w * 128 + ((cq * 8) ^ swz(w));
            *reinterpret_cast<u16x4*>(reinterpret_cast<char*>(xl) + byte) = pk;
        }
    };

    // ---- x rows 0..2 issued FIRST: HBM latency hides under the ingest ----
    f32x4 s0[4], s1[4], s2[4], st[4];
    ldrow(0, s0); ldrow(1, s1); ldrow(2, s2);

    // ---- Fused weight ingest, prep-orientation (R12-verified mapping):
    //      thread owns fragment-slot idx = ((ij*2+cs)*4+of)*64 + l per iter;
    //      8 strided dword reads (c = cs*32 + (l>>4)*8 + j8, o = of*16+(l&15)),
    //      pack u16x8, ONE linear ds_write_b128 at idx*16 (conflict-free).
    u16* wl = xl;                             // 36864 u16 = 72 KB scratch
#pragma unroll
    for (int it = 0; it < 9; ++it) {
        int task = it * 512 + tid;            // < 4608 = 9ij * 2cs * 4of * 64l
        int tl = task & 63;
        int of = (task >> 6) & 3;
        int cs = (task >> 8) & 1;
        int ij = task >> 9;                   // 0..8
        const int o = of * 16 + (tl & 15);
        const int cbase = cs * 32 + (tl >> 4) * 8;
        u16x8 pk;
#pragma unroll
        for (int j8 = 0; j8 < 8; ++j8) {
            float v = wtb[(size_t)(cbase + j8) * 9 * 64 + (size_t)ij * 64 + o];
            pk[j8] = f2bf(v);
        }
        *reinterpret_cast<u16x8*>(wl + (size_t)task * 8) = pk;
    }
    __syncthreads();                          // wl fully written

    bf16x8 wreg[9][2][2];                     // [ij][cs][nf] = 144 regs
#pragma unroll
    for (int ij = 0; ij < 9; ++ij)
#pragma unroll
        for (int cs = 0; cs < 2; ++cs)
#pragma unroll
            for (int nf = 0; nf < 2; ++nf)
                wreg[ij][cs][nf] = *reinterpret_cast<const bf16x8*>(
                    wl + (size_t)(((ij * 2 + cs) * 4 + wave_n * 2 + nf) * 64 + l) * 8);

    const float bv0 = bias[b * 64 + o0 + lr];
    const float bv1 = bias[b * 64 + o0 + 16 + lr];
    __syncthreads();                          // wreg reads done; recycle LDS

    // ---- Prologue staging: slots 0..3, s=4 held in regs for row 0 ----
    wrrow(0, s0); wrrow(1, s1); wrrow(2, s2);
    ldrow(3, s0); ldrow(4, st);
    wrrow(3, s0);
    __syncthreads();

    // ---- 8 output rows; row r reads slots (r..r+2)%6 ----
    int slA = 0;                              // r % 6, tracked incrementally
#pragma unroll 1
    for (int r = 0; r < 8; ++r) {
        const int slB = (slA + 1 == 6) ? 0 : slA + 1;
        const int slC = (slB + 1 == 6) ? 0 : slB + 1;
        const int slW = (slC + 2 >= 6) ? slC + 2 - 6 : slC + 2;   // (r+4)%6
        const int base0 = slA * 16384, base1 = slB * 16384, base2 = slC * 16384;

        f32x4 acc[2][2];
#pragma unroll
        for (int mf = 0; mf < 2; ++mf)
#pragma unroll
            for (int nf = 0; nf < 2; ++nf)
                acc[mf][nf] = (f32x4){0.f, 0.f, 0.f, 0.f};

#pragma unroll
        for (int ij = 0; ij < 9; ++ij) {
            if (ij == 0 && r < 6) wrrow(slW, st);     // data loaded last row
            if (ij == 3 && r < 5) ldrow(r + 5, st);   // consumed next row

            const int i = ij / 3;
            const int jsh = ij % 3 - 1;
            const int rbase = (i == 0) ? base0 : (i == 1) ? base1 : base2;
#pragma unroll
            for (int cs = 0; cs < 2; ++cs) {
                const int cb = cs * 64 + lg * 16;
                bf16x8 afr[2];
#pragma unroll
                for (int mf = 0; mf < 2; ++mf) {
                    int w = (m0 + mf * 16 + lr + jsh + 128) & 127;
                    int byte = rbase + w * 128 + (cb ^ swz(w));
                    afr[mf] = *reinterpret_cast<const bf16x8*>(
                        reinterpret_cast<const char*>(xl) + byte);
                }
#pragma unroll
                for (int mf = 0; mf < 2; ++mf) {
                    acc[mf][0] = __builtin_amdgcn_mfma_f32_16x16x32_bf16(afr[mf], wreg[ij][cs][0], acc[mf][0], 0, 0, 0);
                    acc[mf][1] = __builtin_amdgcn_mfma_f32_16x16x32_bf16(afr[mf], wreg[ij][cs][1], acc[mf][1], 0, 0, 0);
                }
            }
        }

        // ---- Epilogue: D layout col=lane&15 (o), row=(lane>>4)*4+reg (w) ----
        const int h = h0 + r;
#pragma unroll
        for (int nf = 0; nf < 2; ++nf) {
            int o = o0 + nf * 16 + lr;
            float bv = nf ? bv1 : bv0;
#pragma unroll
            for (int mf = 0; mf < 2; ++mf) {
                int w0 = m0 + mf * 16 + lg * 4;
                float* dst = y + (((size_t)b * 64 + o) * 128 + h) * 128 + w0;
                f32x4 out;
                out[0] = acc[mf][nf][0] + bv;
                out[1] = acc[mf][nf][1] + bv;
                out[2] = acc[mf][nf][2] + bv;
                out[3] = acc[mf][nf][3] + bv;
                *reinterpret_cast<f32x4*>(dst) = out;
            }
        }

        // Barrier every 2 rows (after rows 1,3,5). Hazard ledger: a slot
        // written at row r is first read at row r+2 and last-read-before-
        // overwrite at row r-2 -> one barrier inside each 2-row window in
        // both directions suffices (checked per slot for r=0..7).
        if ((r & 1) && r < 7) __syncthreads();
        slA = slB;
    }
}

extern "C" void kernel_launch(void* const* d_in, const int* in_sizes, int n_in,
                              void* d_out, int out_size, void* d_ws, size_t ws_size,
                              hipStream_t stream) {
    const float* x    = (const float*)d_in[0];
    const float* wt   = (const float*)d_in[1];
    const float* bias = (const float*)d_in[2];
    float* y = (float*)d_out;
    (void)d_ws; (void)ws_size;                // fused kernel needs no workspace

    hipLaunchKernelGGL(conv_main, dim3(B_N * H_N / 8), dim3(512), 0, stream,
                       x, wt, bias, y);
}